// Round 3
// baseline (392.579 us; speedup 1.0000x reference)
//
#include <hip/hip_runtime.h>
#include <math.h>

// ---------------------------------------------------------------------------
// QuantumCritic R3.
//   prep_weights: one launch, role by blockIdx:
//     [0,128)   prep_W: circuit on 256 basis cols (gates computed inline)
//               -> Bmat[c][n=512(re|im)][k=256] bf16
//     [128,192) w1pack: w1 split hi/lo into 32x32x16 A-frag order (transposed)
//     [192,200) w2pack: w2 split hi/lo into A-frag order (rows=e, padded to 32)
//     [200,712) Gmat:   G[c][n][i] = sum_q sign_q(i) w3[q][n]  bf16
//   enc_mfma: split-bf16 MFMA GEMM x@w1 (transposed C: row=n, col=batch),
//             bias+relu in regs, GEMM2 w2T*hT straight from acc regs
//             (cndmask + shfl_xor(32) half-swap), cross-wave LDS reduce -> enc.
//   qgemm: unchanged semantics from R2 (validated), but unroll-capped to kill
//          VGPR spill: stage1 unroll 4, stage2 unroll 8, one barrier removed.
// ---------------------------------------------------------------------------

typedef __attribute__((ext_vector_type(8))) short bfrag_t;   // 8 bf16 = 4 VGPR
typedef __attribute__((ext_vector_type(16))) float accv_t;   // 32x32 MFMA acc

__device__ __forceinline__ unsigned short f2bf(float x) {
  unsigned u = __float_as_uint(x);
  u += 0x7FFFu + ((u >> 16) & 1u);      // RNE
  return (unsigned short)(u >> 16);
}
__device__ __forceinline__ float bf2f(unsigned short h) {
  return __uint_as_float(((unsigned)h) << 16);
}
__device__ __forceinline__ unsigned pack2(float a, float b) {
  return (unsigned)f2bf(a) | ((unsigned)f2bf(b) << 16);
}

struct C2 { float r, i; };
__device__ __forceinline__ C2 cmul(C2 a, C2 b){ return C2{a.r*b.r - a.i*b.i, a.r*b.i + a.i*b.r}; }
__device__ __forceinline__ C2 cadd(C2 a, C2 b){ return C2{a.r+b.r, a.i+b.i}; }

#define APPLY2(A,Bx)                                                        \
  { float ar=re[A], ai=im[A], br=re[Bx], bi=im[Bx];                         \
    re[A]  = u00r*ar - u00i*ai + u01r*br - u01i*bi;                         \
    im[A]  = u00r*ai + u00i*ar + u01r*bi + u01i*br;                         \
    re[Bx] = u10r*ar - u10i*ai + u11r*br - u11i*bi;                         \
    im[Bx] = u10r*ai + u10i*ar + u11r*bi + u11i*br; }

__global__ __launch_bounds__(256)
void prep_weights(const float* __restrict__ qrxa, const float* __restrict__ qrya,
                  const float* __restrict__ qrza,
                  const float* __restrict__ qrxb, const float* __restrict__ qryb,
                  const float* __restrict__ qrzb,
                  const float* __restrict__ w1a, const float* __restrict__ w1b,
                  const float* __restrict__ w2a, const float* __restrict__ w2b,
                  const float* __restrict__ w3a, const float* __restrict__ w3b,
                  unsigned short* __restrict__ Bm, unsigned short* __restrict__ Gm,
                  unsigned short* __restrict__ w1p, unsigned short* __restrict__ w2p) {
  int blk = blockIdx.x;
  int tid = threadIdx.x;
  if (blk < 128) {
    // ---- prep_W with inline gate fusion ----
    __shared__ float sg[192];    // 24 gates x 8 for this block's critic
    int c = blk >> 6;
    if (tid < 24) {
      const float* qx = c ? qrxb : qrxa;
      const float* qy = c ? qryb : qrya;
      const float* qz = c ? qrzb : qrza;
      int g = tid;
      float tx = 0.5f*qx[g], ty = 0.5f*qy[g], tz = 0.5f*qz[g];
      float cx = cosf(tx), sx = sinf(tx);
      float cy = cosf(ty), sy = sinf(ty);
      float cz = cosf(tz), sz = sinf(tz);
      C2 rx00{cx,0.f}, rx01{0.f,-sx}, rx10{0.f,-sx}, rx11{cx,0.f};
      C2 m00 = cadd(cmul(C2{cy,0.f},rx00), cmul(C2{-sy,0.f},rx10));
      C2 m01 = cadd(cmul(C2{cy,0.f},rx01), cmul(C2{-sy,0.f},rx11));
      C2 m10 = cadd(cmul(C2{sy,0.f},rx00), cmul(C2{cy,0.f},rx10));
      C2 m11 = cadd(cmul(C2{sy,0.f},rx01), cmul(C2{cy,0.f},rx11));
      C2 e0{cz,-sz}, e1{cz,sz};
      C2 u00 = cmul(e0,m00), u01 = cmul(e0,m01), u10 = cmul(e1,m10), u11 = cmul(e1,m11);
      float* o = sg + g*8;
      o[0]=u00.r; o[1]=u00.i; o[2]=u01.r; o[3]=u01.i;
      o[4]=u10.r; o[5]=u10.i; o[6]=u11.r; o[7]=u11.i;
    }
    __syncthreads();
    int lane = tid & 63;
    int wid = blk*4 + (tid >> 6);
    int bcol = wid & 255;
    int p = __popc(bcol) & 3;
    float phr = (p==0) ? 1.f : ((p==2) ? -1.f : 0.f);
    float phi = (p==1) ? -1.f : ((p==3) ? 1.f : 0.f);
    float re[4], im[4];
    #pragma unroll
    for (int j = 0; j < 4; ++j) {
      int idx = 4*lane + j;
      re[j] = (idx==bcol) ? phr : 0.f;
      im[j] = (idx==bcol) ? phi : 0.f;
    }
    #pragma unroll
    for (int l = 0; l < 3; ++l) {
      #pragma unroll
      for (int q = 0; q < 8; ++q) {
        const float* u = &sg[(size_t)(l*8 + q)*8];
        float u00r=u[0],u00i=u[1],u01r=u[2],u01i=u[3];
        float u10r=u[4],u10i=u[5],u11r=u[6],u11i=u[7];
        if (q < 6) {
          int m = 5-q, mask = 1<<m;
          bool s1 = ((lane >> m) & 1) != 0;
          float udr = s1?u11r:u00r, udi = s1?u11i:u00i;
          float uor = s1?u10r:u01r, uoi = s1?u10i:u01i;
          #pragma unroll
          for (int j = 0; j < 4; ++j) {
            float pr = __shfl_xor(re[j], mask);
            float pi = __shfl_xor(im[j], mask);
            float nr = udr*re[j] - udi*im[j] + uor*pr - uoi*pi;
            float ni = udr*im[j] + udi*re[j] + uor*pi + uoi*pr;
            re[j]=nr; im[j]=ni;
          }
        } else if (q == 6) { APPLY2(0,2); APPLY2(1,3); }
        else               { APPLY2(0,1); APPLY2(2,3); }
      }
      #pragma unroll
      for (int cq = 0; cq <= 4; ++cq) {
        int tmask = 1 << (4-cq);
        bool pred = ((lane >> (5-cq)) & 1) != 0;
        #pragma unroll
        for (int j = 0; j < 4; ++j) {
          float sr = __shfl_xor(re[j], tmask);
          float si = __shfl_xor(im[j], tmask);
          re[j] = pred ? sr : re[j];
          im[j] = pred ? si : im[j];
        }
      }
      { bool pred = (lane & 1) != 0;
        float t0, t1;
        t0 = pred?re[2]:re[0]; t1 = pred?re[0]:re[2]; re[0]=t0; re[2]=t1;
        t0 = pred?im[2]:im[0]; t1 = pred?im[0]:im[2]; im[0]=t0; im[2]=t1;
        t0 = pred?re[3]:re[1]; t1 = pred?re[1]:re[3]; re[1]=t0; re[3]=t1;
        t0 = pred?im[3]:im[1]; t1 = pred?im[1]:im[3]; im[1]=t0; im[3]=t1; }
      { float t;
        t=re[2]; re[2]=re[3]; re[3]=t;
        t=im[2]; im[2]=im[3]; im[3]=t; }
      { re[1]=__shfl_xor(re[1],32); im[1]=__shfl_xor(im[1],32);
        re[3]=__shfl_xor(re[3],32); im[3]=__shfl_xor(im[3],32); }
    }
    #pragma unroll
    for (int j = 0; j < 4; ++j) {
      int i = 4*lane + j;
      Bm[(size_t)(c*512 + i)*256 + bcol]       = f2bf(re[j]);
      Bm[(size_t)(c*512 + 256 + i)*256 + bcol] = f2bf(im[j]);
    }
  } else if (blk < 192) {
    // ---- w1pack: slot = c*8192 + p*4096 + ks*512 + h5*256 + n ----
    int slot = (blk-128)*256 + tid;
    int n = slot & 255, h5 = (slot>>8)&1, ks = (slot>>9)&7, p = (slot>>12)&1, c = slot>>13;
    const float* w1c = c ? w1b : w1a;
    #pragma unroll
    for (int j = 0; j < 8; ++j) {
      float v = w1c[(size_t)(ks*16 + h5*8 + j)*256 + n];
      unsigned short hi = f2bf(v);
      w1p[(size_t)slot*8 + j] = p ? f2bf(v - bf2f(hi)) : hi;
    }
  } else if (blk < 200) {
    // ---- w2pack: combo = c*64 + p*32 + k16*2 + h5; 256 elems = il*8+j ----
    int slot = (blk-192)*256 + tid;         // [0, 2048)
    int combo = slot >> 4, part = slot & 15;
    int h5 = combo&1, k16 = (combo>>1)&15, p = (combo>>5)&1, c = (combo>>6)&1;
    const float* w2c = c ? w2b : w2a;
    #pragma unroll
    for (int jj = 0; jj < 16; ++jj) {
      int idx = part*16 + jj;
      int il = idx >> 3, j = idx & 7;
      int n = k16*16 + h5*8 + j;
      float v = (il < 8) ? w2c[(size_t)n*8 + il] : 0.f;
      unsigned short hi = f2bf(v);
      w2p[(size_t)combo*256 + idx] = p ? f2bf(v - bf2f(hi)) : hi;
    }
  } else {
    // ---- Gmat ----
    int idx = (blk-200)*256 + tid;          // [0, 131072)
    int c = idx >> 16, rem = idx & 65535, n = rem >> 8, i = rem & 255;
    const float* w3 = c ? w3b : w3a;
    float s = 0.f;
    #pragma unroll
    for (int q = 0; q < 8; ++q) {
      float sg2 = ((i >> (7-q)) & 1) ? -1.f : 1.f;
      s += sg2 * w3[q*256 + n];
    }
    Gm[(size_t)(c*256 + n)*256 + i] = f2bf(s);
  }
}

// ---------------------------------------------------------------------------
// enc_mfma: 256 thr = 4 waves, 64 batch rows/block, 1024 blocks.
// GEMM1-T (split bf16): C[n][m] = sum_k w1[k][n] x[m][k]; wave w owns n-tiles
// {2w, 2w+1}, both m-tiles. GEMM2-T: enc^T = w2^T * h^T via 32x32x16 with
// B-frags assembled from acc regs (cndmask + shfl_xor 32).
// ---------------------------------------------------------------------------
__global__ __launch_bounds__(256, 3)
void enc_mfma(const float* __restrict__ state, const float* __restrict__ action,
              const unsigned short* __restrict__ w1p,
              const float* __restrict__ b1a, const float* __restrict__ b1b,
              const unsigned short* __restrict__ w2p,
              const float* __restrict__ b2a, const float* __restrict__ b2b,
              float* __restrict__ enc, int Bn) {
  __shared__ __align__(16) char Bx[2][16384];     // [prec][ks*2048 + m*32 + kq*8]
  __shared__ __align__(16) float sb1[2][256];
  __shared__ float sb2[2][8];
  __shared__ __align__(16) float encw[4][2][32][8]; // wave, mt, il, e
  int tid = threadIdx.x;
  int lane = tid & 63, w = tid >> 6, il = lane & 31, h5 = lane >> 5;
  int r0 = blockIdx.x * 64;

  sb1[0][tid] = b1a[tid];
  sb1[1][tid] = b1b[tid];
  if (tid < 8) { sb2[0][tid] = b2a[tid]; sb2[1][tid] = b2b[tid]; }

  { // stage x split hi/lo into B-frag order
    int m = tid >> 2, kq = tid & 3;
    const float4* st4 = (const float4*)state;
    const float4* ac4 = (const float4*)action;
    #pragma unroll
    for (int ks = 0; ks < 8; ++ks) {
      float4 v = (ks < 6) ? st4[(size_t)(r0+m)*24 + ks*4 + kq]
                          : ac4[(size_t)(r0+m)*8 + (ks-6)*4 + kq];
      unsigned short hx = f2bf(v.x), hy = f2bf(v.y), hz = f2bf(v.z), hw = f2bf(v.w);
      uint2 hh, ll;
      hh.x = (unsigned)hx | ((unsigned)hy << 16);
      hh.y = (unsigned)hz | ((unsigned)hw << 16);
      ll.x = (unsigned)f2bf(v.x - bf2f(hx)) | ((unsigned)f2bf(v.y - bf2f(hy)) << 16);
      ll.y = (unsigned)f2bf(v.z - bf2f(hz)) | ((unsigned)f2bf(v.w - bf2f(hw)) << 16);
      int off = ks*2048 + m*32 + kq*8;
      *(uint2*)(&Bx[0][off]) = hh;
      *(uint2*)(&Bx[1][off]) = ll;
    }
  }
  __syncthreads();

  for (int c = 0; c < 2; ++c) {
    accv_t A[2][2] = {{{},{}},{{},{}}};   // [nt][mt]
    // ---- GEMM1-T ----
    #pragma unroll
    for (int ks = 0; ks < 8; ++ks) {
      bfrag_t a0h, a0l, a1h, a1l;
      {
        size_t b0 = ((size_t)((c*2+0)*8 + ks)*2 + h5)*256;
        size_t b1 = ((size_t)((c*2+1)*8 + ks)*2 + h5)*256;
        int t0 = 2*w, t1 = 2*w+1;
        a0h = *(const bfrag_t*)(w1p + (b0 + t0*32 + il)*8);
        a0l = *(const bfrag_t*)(w1p + (b1 + t0*32 + il)*8);
        a1h = *(const bfrag_t*)(w1p + (b0 + t1*32 + il)*8);
        a1l = *(const bfrag_t*)(w1p + (b1 + t1*32 + il)*8);
      }
      bfrag_t b0h = *(const bfrag_t*)(&Bx[0][ks*2048 + il*32 + h5*16]);
      bfrag_t b0l = *(const bfrag_t*)(&Bx[1][ks*2048 + il*32 + h5*16]);
      bfrag_t b1h_ = *(const bfrag_t*)(&Bx[0][ks*2048 + (32+il)*32 + h5*16]);
      bfrag_t b1l_ = *(const bfrag_t*)(&Bx[1][ks*2048 + (32+il)*32 + h5*16]);
      A[0][0] = __builtin_amdgcn_mfma_f32_32x32x16_bf16(a0h, b0h, A[0][0], 0,0,0);
      A[0][0] = __builtin_amdgcn_mfma_f32_32x32x16_bf16(a0h, b0l, A[0][0], 0,0,0);
      A[0][0] = __builtin_amdgcn_mfma_f32_32x32x16_bf16(a0l, b0h, A[0][0], 0,0,0);
      A[0][1] = __builtin_amdgcn_mfma_f32_32x32x16_bf16(a0h, b1h_, A[0][1], 0,0,0);
      A[0][1] = __builtin_amdgcn_mfma_f32_32x32x16_bf16(a0h, b1l_, A[0][1], 0,0,0);
      A[0][1] = __builtin_amdgcn_mfma_f32_32x32x16_bf16(a0l, b1h_, A[0][1], 0,0,0);
      A[1][0] = __builtin_amdgcn_mfma_f32_32x32x16_bf16(a1h, b0h, A[1][0], 0,0,0);
      A[1][0] = __builtin_amdgcn_mfma_f32_32x32x16_bf16(a1h, b0l, A[1][0], 0,0,0);
      A[1][0] = __builtin_amdgcn_mfma_f32_32x32x16_bf16(a1l, b0h, A[1][0], 0,0,0);
      A[1][1] = __builtin_amdgcn_mfma_f32_32x32x16_bf16(a1h, b1h_, A[1][1], 0,0,0);
      A[1][1] = __builtin_amdgcn_mfma_f32_32x32x16_bf16(a1h, b1l_, A[1][1], 0,0,0);
      A[1][1] = __builtin_amdgcn_mfma_f32_32x32x16_bf16(a1l, b1h_, A[1][1], 0,0,0);
    }
    // ---- bias + relu (h in regs) ----
    #pragma unroll
    for (int nt = 0; nt < 2; ++nt) {
      #pragma unroll
      for (int g = 0; g < 4; ++g) {
        float4 bb = *(const float4*)&sb1[c][(2*w+nt)*32 + 8*g + 4*h5];
        float bba[4] = {bb.x, bb.y, bb.z, bb.w};
        #pragma unroll
        for (int jj = 0; jj < 4; ++jj) {
          A[nt][0][4*g+jj] = fmaxf(A[nt][0][4*g+jj] + bba[jj], 0.f);
          A[nt][1][4*g+jj] = fmaxf(A[nt][1][4*g+jj] + bba[jj], 0.f);
        }
      }
    }
    // ---- GEMM2-T: enc^T = w2^T * h^T ----
    accv_t Cm[2] = {{},{}};
    #pragma unroll
    for (int k2 = 0; k2 < 4; ++k2) {
      int k16 = 4*w + k2;
      bfrag_t g2h = *(const bfrag_t*)(w2p + ((size_t)((c*2+0)*16 + k16)*2 + h5)*256 + il*8);
      bfrag_t g2l = *(const bfrag_t*)(w2p + ((size_t)((c*2+1)*16 + k16)*2 + h5)*256 + il*8);
      #pragma unroll
      for (int mt = 0; mt < 2; ++mt) {
        // packs for G = 2k2 (gi=0) and 2k2+1 (gi=1)
        unsigned ph[2][2], pl[2][2];
        #pragma unroll
        for (int gi = 0; gi < 2; ++gi) {
          int G = 2*k2 + gi, nt = G >> 2, g = G & 3;
          float f0 = A[nt][mt][4*g+0], f1 = A[nt][mt][4*g+1];
          float f2 = A[nt][mt][4*g+2], f3 = A[nt][mt][4*g+3];
          unsigned short h0 = f2bf(f0), h1 = f2bf(f1), h2 = f2bf(f2), h3 = f2bf(f3);
          ph[gi][0] = (unsigned)h0 | ((unsigned)h1 << 16);
          ph[gi][1] = (unsigned)h2 | ((unsigned)h3 << 16);
          pl[gi][0] = (unsigned)f2bf(f0 - bf2f(h0)) | ((unsigned)f2bf(f1 - bf2f(h1)) << 16);
          pl[gi][1] = (unsigned)f2bf(f2 - bf2f(h2)) | ((unsigned)f2bf(f3 - bf2f(h3)) << 16);
        }
        union { bfrag_t v; unsigned u[4]; } FH, FL;
        #pragma unroll
        for (int r = 0; r < 2; ++r) {
          unsigned own_h = h5 ? ph[1][r] : ph[0][r];
          unsigned alt_h = h5 ? ph[0][r] : ph[1][r];
          unsigned rec_h = __shfl_xor((int)alt_h, 32);
          FH.u[r]   = h5 ? rec_h : own_h;
          FH.u[2+r] = h5 ? own_h : rec_h;
          unsigned own_l = h5 ? pl[1][r] : pl[0][r];
          unsigned alt_l = h5 ? pl[0][r] : pl[1][r];
          unsigned rec_l = __shfl_xor((int)alt_l, 32);
          FL.u[r]   = h5 ? rec_l : own_l;
          FL.u[2+r] = h5 ? own_l : rec_l;
        }
        Cm[mt] = __builtin_amdgcn_mfma_f32_32x32x16_bf16(g2h, FH.v, Cm[mt], 0,0,0);
        Cm[mt] = __builtin_amdgcn_mfma_f32_32x32x16_bf16(g2h, FL.v, Cm[mt], 0,0,0);
        Cm[mt] = __builtin_amdgcn_mfma_f32_32x32x16_bf16(g2l, FH.v, Cm[mt], 0,0,0);
      }
    }
    // ---- cross-wave reduce ----
    *(float4*)&encw[w][0][il][4*h5] = make_float4(Cm[0][0], Cm[0][1], Cm[0][2], Cm[0][3]);
    *(float4*)&encw[w][1][il][4*h5] = make_float4(Cm[1][0], Cm[1][1], Cm[1][2], Cm[1][3]);
    __syncthreads();
    #pragma unroll
    for (int half = 0; half < 2; ++half) {
      int s = tid + half*256;
      int e = s & 7, mm = s >> 3;
      float v = sb2[c][e];
      #pragma unroll
      for (int ww = 0; ww < 4; ++ww) v += encw[ww][mm>>5][mm&31][e];
      enc[((size_t)c*Bn + r0 + mm)*8 + e] = v;
    }
    __syncthreads();   // encw reused by next critic
  }
}

// ---------------------------------------------------------------------------
// qgemm: semantics identical to validated R2; unroll-capped to avoid spill.
// ---------------------------------------------------------------------------
__global__ __launch_bounds__(512, 2)
void qgemm(const float* __restrict__ enc,
           const unsigned short* __restrict__ Bm, const unsigned short* __restrict__ Gm,
           const float* __restrict__ b3a, const float* __restrict__ w4a, const float* __restrict__ b4a,
           const float* __restrict__ b3b, const float* __restrict__ w4b, const float* __restrict__ b4b,
           float* __restrict__ out, int Bn) {
  __shared__ __align__(16) char Alds[16384];    // 16 ks * 1024
  __shared__ __align__(16) char Plds[16640];    // 16 ks * 1040
  __shared__ __align__(16) float cs[32*18];
  __shared__ float redbuf[8][32];

  int tid = threadIdx.x;
  int lane = tid & 63;
  int w = tid >> 6;
  int il = lane & 31;
  int khalf = (lane >> 5) * 8;

  int bx = blockIdx.x;
  int c = bx >> 8;
  int rowblock = bx & 255;
  int rowsPerBlock = Bn >> 8;
  int subtiles = rowsPerBlock >> 5;

  bfrag_t bf0[16], bf1[16];
  {
    const unsigned short* base = Bm + ((size_t)(c*512 + 32*w + il)*256 + khalf);
    #pragma unroll
    for (int ks = 0; ks < 16; ++ks) {
      bf0[ks] = *(const bfrag_t*)(base + ks*16);
      bf1[ks] = *(const bfrag_t*)(base + 256*256 + ks*16);
    }
  }
  int n2 = 32*w + il;
  const float* b3c = c ? b3b : b3a;
  const float* w4c = c ? w4b : w4a;
  const float* b4c = c ? b4b : b4a;
  float b3v = b3c[n2];
  float w4v = w4c[n2];
  float b4v = b4c[0];
  const unsigned short* Gbase = Gm + ((size_t)(c*256 + n2)*256 + khalf);
  int pwbase = (n2>>4)*1040 + ((n2>>3)&1)*512 + (n2&7)*2;
  int rowAdd = 4*(lane>>5);

  for (int st = 0; st < subtiles; ++st) {
    int r0 = rowblock*rowsPerBlock + st*32;
    // ---- phase A: sincos ----
    if (tid < 256) {
      int m = tid & 31, q = tid >> 5;
      float e = enc[((size_t)c*Bn + r0 + m)*8 + q];
      float sv, cv;
      __sincosf(0.5f*e, &sv, &cv);
      cs[m*18 + q*2]     = cv;
      cs[m*18 + q*2 + 1] = sv;
    }
    __syncthreads();                                   // (b)
    // ---- phase B: build R in frag-order LDS ----
    {
      int m = tid & 31, g2 = tid >> 5;
      float2 q0 = *(float2*)&cs[m*18 + 0];
      float2 q1 = *(float2*)&cs[m*18 + 2];
      float2 q2 = *(float2*)&cs[m*18 + 4];
      float2 q3 = *(float2*)&cs[m*18 + 6];
      float2 q4 = *(float2*)&cs[m*18 + 8];
      float2 q5 = *(float2*)&cs[m*18 + 10];
      float2 q6 = *(float2*)&cs[m*18 + 12];
      float2 q7 = *(float2*)&cs[m*18 + 14];
      float v0 = (g2&8) ? q0.y : q0.x;
      float v1 = (g2&4) ? q1.y : q1.x;
      float v2 = (g2&2) ? q2.y : q2.x;
      float v3 = (g2&1) ? q3.y : q3.x;
      float top = v0*v1*v2*v3;
      float hA = top*q4.x, hB = top*q4.y;
      float p67[4];
      p67[0] = q6.x*q7.x; p67[1] = q6.x*q7.y;
      p67[2] = q6.y*q7.x; p67[3] = q6.y*q7.y;
      float low[8];
      #pragma unroll
      for (int j = 0; j < 8; ++j) low[j] = ((j&4) ? q5.y : q5.x) * p67[j&3];
      union { bfrag_t v; unsigned u[4]; } pk;
      #pragma unroll
      for (int k = 0; k < 4; ++k) pk.u[k] = pack2(hA*low[2*k], hA*low[2*k+1]);
      *(bfrag_t*)(Alds + g2*1024 + m*16) = pk.v;
      #pragma unroll
      for (int k = 0; k < 4; ++k) pk.u[k] = pack2(hB*low[2*k], hB*low[2*k+1]);
      *(bfrag_t*)(Alds + g2*1024 + 512 + m*16) = pk.v;
    }
    __syncthreads();                                   // (c)
    // ---- stage 1 ----
    accv_t acc0 = {}, acc1 = {};
    #pragma unroll 4
    for (int ks = 0; ks < 16; ++ks) {
      bfrag_t af = *(const bfrag_t*)(Alds + ks*1024 + lane*16);
      acc0 = __builtin_amdgcn_mfma_f32_32x32x16_bf16(af, bf0[ks], acc0, 0, 0, 0);
      acc1 = __builtin_amdgcn_mfma_f32_32x32x16_bf16(af, bf1[ks], acc1, 0, 0, 0);
    }
    #pragma unroll
    for (int r = 0; r < 16; ++r) {
      float P = acc0[r]*acc0[r] + acc1[r]*acc1[r];
      int row = (r&3) + 8*(r>>2) + rowAdd;
      *(unsigned short*)(Plds + pwbase + row*16) = f2bf(P);
    }
    __syncthreads();                                   // (d)
    // ---- stage 2 ----
    accv_t acc2 = {};
    #pragma unroll 8
    for (int ks = 0; ks < 16; ++ks) {
      bfrag_t pf = *(const bfrag_t*)(Plds + ks*1040 + lane*16);
      bfrag_t gf = *(const bfrag_t*)(Gbase + ks*16);
      acc2 = __builtin_amdgcn_mfma_f32_32x32x16_bf16(pf, gf, acc2, 0, 0, 0);
    }
    // ---- epilogue ----
    float qp[16];
    #pragma unroll
    for (int r = 0; r < 16; ++r) {
      float h2 = fmaxf(acc2[r] + b3v, 0.f);
      qp[r] = h2 * w4v;
    }
    #pragma unroll
    for (int mask = 1; mask <= 16; mask <<= 1)
      #pragma unroll
      for (int r = 0; r < 16; ++r) qp[r] += __shfl_xor(qp[r], mask);
    if (il == 0) {
      #pragma unroll
      for (int r = 0; r < 16; ++r)
        redbuf[w][(r&3) + 8*(r>>2) + rowAdd] = qp[r];
    }
    __syncthreads();                                   // (e)
    if (tid < 32) {
      float s = b4v;
      #pragma unroll
      for (int ww = 0; ww < 8; ++ww) s += redbuf[ww][tid];
      out[(size_t)c*Bn + r0 + tid] = s;
    }
  }
}

extern "C" void kernel_launch(void* const* d_in, const int* in_sizes, int n_in,
                              void* d_out, int out_size, void* d_ws, size_t ws_size,
                              hipStream_t stream) {
  (void)n_in; (void)out_size; (void)ws_size;
  const float* state  = (const float*)d_in[0];
  const float* action = (const float*)d_in[1];
  const float* w1a=(const float*)d_in[2];  const float* b1a=(const float*)d_in[3];
  const float* w2a=(const float*)d_in[4];  const float* b2a=(const float*)d_in[5];
  const float* qrxa=(const float*)d_in[6]; const float* qrya=(const float*)d_in[7];
  const float* qrza=(const float*)d_in[8];
  const float* w3a=(const float*)d_in[9];  const float* b3a=(const float*)d_in[10];
  const float* w4a=(const float*)d_in[11]; const float* b4a=(const float*)d_in[12];
  const float* w1b=(const float*)d_in[13]; const float* b1b=(const float*)d_in[14];
  const float* w2b=(const float*)d_in[15]; const float* b2b=(const float*)d_in[16];
  const float* qrxb=(const float*)d_in[17];const float* qryb=(const float*)d_in[18];
  const float* qrzb=(const float*)d_in[19];
  const float* w3b=(const float*)d_in[20]; const float* b3b=(const float*)d_in[21];
  const float* w4b=(const float*)d_in[22]; const float* b4b=(const float*)d_in[23];

  int B = in_sizes[0] / 96;
  char* wsb = (char*)d_ws;
  unsigned short* Bmat = (unsigned short*)(wsb);                 // 524288 B
  unsigned short* Gmat = (unsigned short*)(wsb + 524288);        // 262144 B
  unsigned short* w1p  = (unsigned short*)(wsb + 786432);        // 262144 B
  unsigned short* w2p  = (unsigned short*)(wsb + 1048576);       // 65536 B
  float* enc           = (float*)(wsb + 1114112);                // 2*B*8*4 B

  prep_weights<<<712, 256, 0, stream>>>(qrxa,qrya,qrza,qrxb,qryb,qrzb,
                                        w1a,w1b,w2a,w2b,w3a,w3b,
                                        Bmat,Gmat,w1p,w2p);
  enc_mfma<<<B/64, 256, 0, stream>>>(state,action,w1p,b1a,b1b,w2p,b2a,b2b,enc,B);
  qgemm<<<512, 512, 0, stream>>>(enc, Bmat, Gmat, b3a, w4a, b4a, b3b, w4b, b4b,
                                 (float*)d_out, B);
}

// Round 4
// 228.730 us; speedup vs baseline: 1.7163x; 1.7163x over previous
//
#include <hip/hip_runtime.h>
#include <math.h>

// ---------------------------------------------------------------------------
// QuantumCritic R4.
//   psi = W r (W = U*D fixed 256x256 complex bf16, r real product vector)
//   P = |psi|^2 ; ex@w3 = P @ G (G = S^T w3 fixed bf16)
// R4 changes vs R3 (spill post-mortem):
//   - qgemm: only W-frags register-resident (128 VGPR). G read per subtile,
//     coalesced frag-order layout (written by prep). Stage1 fully unrolled
//     (constant bf0/bf1 indices — partial unroll demotes arrays to scratch,
//     R3's 537MB FETCH bug). Stage2 partial unroll (no persistent arrays).
//     sincos merged into A-build; epilogue butterfly -> LDS qtmp reduce.
//     LDS 32KB total (A 16K | P 16K, reused as qtmp fp32 32K).
//   - enc_mfma: launch_bounds (256,3)->(256,2); LDS already caps at 2 blk/CU,
//     the 170-VGPR cap only risked spill.
// ---------------------------------------------------------------------------

typedef __attribute__((ext_vector_type(8))) short bfrag_t;   // 8 bf16 = 4 VGPR
typedef __attribute__((ext_vector_type(16))) float accv_t;   // 32x32 MFMA acc

__device__ __forceinline__ unsigned short f2bf(float x) {
  unsigned u = __float_as_uint(x);
  u += 0x7FFFu + ((u >> 16) & 1u);      // RNE
  return (unsigned short)(u >> 16);
}
__device__ __forceinline__ float bf2f(unsigned short h) {
  return __uint_as_float(((unsigned)h) << 16);
}
__device__ __forceinline__ unsigned pack2(float a, float b) {
  return (unsigned)f2bf(a) | ((unsigned)f2bf(b) << 16);
}

struct C2 { float r, i; };
__device__ __forceinline__ C2 cmul(C2 a, C2 b){ return C2{a.r*b.r - a.i*b.i, a.r*b.i + a.i*b.r}; }
__device__ __forceinline__ C2 cadd(C2 a, C2 b){ return C2{a.r+b.r, a.i+b.i}; }

#define APPLY2(A,Bx)                                                        \
  { float ar=re[A], ai=im[A], br=re[Bx], bi=im[Bx];                         \
    re[A]  = u00r*ar - u00i*ai + u01r*br - u01i*bi;                         \
    im[A]  = u00r*ai + u00i*ar + u01r*bi + u01i*br;                         \
    re[Bx] = u10r*ar - u10i*ai + u11r*br - u11i*bi;                         \
    im[Bx] = u10r*ai + u10i*ar + u11r*bi + u11i*br; }

__global__ __launch_bounds__(256)
void prep_weights(const float* __restrict__ qrxa, const float* __restrict__ qrya,
                  const float* __restrict__ qrza,
                  const float* __restrict__ qrxb, const float* __restrict__ qryb,
                  const float* __restrict__ qrzb,
                  const float* __restrict__ w1a, const float* __restrict__ w1b,
                  const float* __restrict__ w2a, const float* __restrict__ w2b,
                  const float* __restrict__ w3a, const float* __restrict__ w3b,
                  unsigned short* __restrict__ Bm, unsigned short* __restrict__ Gm,
                  unsigned short* __restrict__ w1p, unsigned short* __restrict__ w2p) {
  int blk = blockIdx.x;
  int tid = threadIdx.x;
  if (blk < 128) {
    // ---- prep_W: circuit on 256 basis columns ----
    __shared__ float sg[192];
    int c = blk >> 6;
    if (tid < 24) {
      const float* qx = c ? qrxb : qrxa;
      const float* qy = c ? qryb : qrya;
      const float* qz = c ? qrzb : qrza;
      int g = tid;
      float tx = 0.5f*qx[g], ty = 0.5f*qy[g], tz = 0.5f*qz[g];
      float cx = cosf(tx), sx = sinf(tx);
      float cy = cosf(ty), sy = sinf(ty);
      float cz = cosf(tz), sz = sinf(tz);
      C2 rx00{cx,0.f}, rx01{0.f,-sx}, rx10{0.f,-sx}, rx11{cx,0.f};
      C2 m00 = cadd(cmul(C2{cy,0.f},rx00), cmul(C2{-sy,0.f},rx10));
      C2 m01 = cadd(cmul(C2{cy,0.f},rx01), cmul(C2{-sy,0.f},rx11));
      C2 m10 = cadd(cmul(C2{sy,0.f},rx00), cmul(C2{cy,0.f},rx10));
      C2 m11 = cadd(cmul(C2{sy,0.f},rx01), cmul(C2{cy,0.f},rx11));
      C2 e0{cz,-sz}, e1{cz,sz};
      C2 u00 = cmul(e0,m00), u01 = cmul(e0,m01), u10 = cmul(e1,m10), u11 = cmul(e1,m11);
      float* o = sg + g*8;
      o[0]=u00.r; o[1]=u00.i; o[2]=u01.r; o[3]=u01.i;
      o[4]=u10.r; o[5]=u10.i; o[6]=u11.r; o[7]=u11.i;
    }
    __syncthreads();
    int lane = tid & 63;
    int wid = blk*4 + (tid >> 6);
    int bcol = wid & 255;
    int p = __popc(bcol) & 3;
    float phr = (p==0) ? 1.f : ((p==2) ? -1.f : 0.f);
    float phi = (p==1) ? -1.f : ((p==3) ? 1.f : 0.f);
    float re[4], im[4];
    #pragma unroll
    for (int j = 0; j < 4; ++j) {
      int idx = 4*lane + j;
      re[j] = (idx==bcol) ? phr : 0.f;
      im[j] = (idx==bcol) ? phi : 0.f;
    }
    #pragma unroll
    for (int l = 0; l < 3; ++l) {
      #pragma unroll
      for (int q = 0; q < 8; ++q) {
        const float* u = &sg[(size_t)(l*8 + q)*8];
        float u00r=u[0],u00i=u[1],u01r=u[2],u01i=u[3];
        float u10r=u[4],u10i=u[5],u11r=u[6],u11i=u[7];
        if (q < 6) {
          int m = 5-q, mask = 1<<m;
          bool s1 = ((lane >> m) & 1) != 0;
          float udr = s1?u11r:u00r, udi = s1?u11i:u00i;
          float uor = s1?u10r:u01r, uoi = s1?u10i:u01i;
          #pragma unroll
          for (int j = 0; j < 4; ++j) {
            float pr = __shfl_xor(re[j], mask);
            float pi = __shfl_xor(im[j], mask);
            float nr = udr*re[j] - udi*im[j] + uor*pr - uoi*pi;
            float ni = udr*im[j] + udi*re[j] + uor*pi + uoi*pr;
            re[j]=nr; im[j]=ni;
          }
        } else if (q == 6) { APPLY2(0,2); APPLY2(1,3); }
        else               { APPLY2(0,1); APPLY2(2,3); }
      }
      #pragma unroll
      for (int cq = 0; cq <= 4; ++cq) {
        int tmask = 1 << (4-cq);
        bool pred = ((lane >> (5-cq)) & 1) != 0;
        #pragma unroll
        for (int j = 0; j < 4; ++j) {
          float sr = __shfl_xor(re[j], tmask);
          float si = __shfl_xor(im[j], tmask);
          re[j] = pred ? sr : re[j];
          im[j] = pred ? si : im[j];
        }
      }
      { bool pred = (lane & 1) != 0;
        float t0, t1;
        t0 = pred?re[2]:re[0]; t1 = pred?re[0]:re[2]; re[0]=t0; re[2]=t1;
        t0 = pred?im[2]:im[0]; t1 = pred?im[0]:im[2]; im[0]=t0; im[2]=t1;
        t0 = pred?re[3]:re[1]; t1 = pred?re[1]:re[3]; re[1]=t0; re[3]=t1;
        t0 = pred?im[3]:im[1]; t1 = pred?im[1]:im[3]; im[1]=t0; im[3]=t1; }
      { float t;
        t=re[2]; re[2]=re[3]; re[3]=t;
        t=im[2]; im[2]=im[3]; im[3]=t; }
      { re[1]=__shfl_xor(re[1],32); im[1]=__shfl_xor(im[1],32);
        re[3]=__shfl_xor(re[3],32); im[3]=__shfl_xor(im[3],32); }
    }
    #pragma unroll
    for (int j = 0; j < 4; ++j) {
      int i = 4*lane + j;
      Bm[(size_t)(c*512 + i)*256 + bcol]       = f2bf(re[j]);
      Bm[(size_t)(c*512 + 256 + i)*256 + bcol] = f2bf(im[j]);
    }
  } else if (blk < 192) {
    // ---- w1pack ----
    int slot = (blk-128)*256 + tid;
    int n = slot & 255, h5 = (slot>>8)&1, ks = (slot>>9)&7, p = (slot>>12)&1, c = slot>>13;
    const float* w1c = c ? w1b : w1a;
    #pragma unroll
    for (int j = 0; j < 8; ++j) {
      float v = w1c[(size_t)(ks*16 + h5*8 + j)*256 + n];
      unsigned short hi = f2bf(v);
      w1p[(size_t)slot*8 + j] = p ? f2bf(v - bf2f(hi)) : hi;
    }
  } else if (blk < 200) {
    // ---- w2pack ----
    int slot = (blk-192)*256 + tid;
    int combo = slot >> 4, part = slot & 15;
    int h5 = combo&1, k16 = (combo>>1)&15, p = (combo>>5)&1, c = (combo>>6)&1;
    const float* w2c = c ? w2b : w2a;
    #pragma unroll
    for (int jj = 0; jj < 16; ++jj) {
      int idx = part*16 + jj;
      int il = idx >> 3, j = idx & 7;
      int n = k16*16 + h5*8 + j;
      float v = (il < 8) ? w2c[(size_t)n*8 + il] : 0.f;
      unsigned short hi = f2bf(v);
      w2p[(size_t)combo*256 + idx] = p ? f2bf(v - bf2f(hi)) : hi;
    }
  } else {
    // ---- Gmat in qgemm frag order:
    // Gm[((c*8+w)*16+ks)*512 + lane*8 + j] = G[n=32w+(lane&31)][i=ks*16+(lane>>5)*8+j]
    int idx = (blk-200)*256 + tid;          // [0, 131072)
    int c = idx >> 16, w = (idx >> 13) & 7, ks = (idx >> 9) & 15;
    int l = (idx >> 3) & 63, j = idx & 7;
    int n = 32*w + (l & 31);
    int i = ks*16 + (l >> 5)*8 + j;
    const float* w3 = c ? w3b : w3a;
    float s = 0.f;
    #pragma unroll
    for (int q = 0; q < 8; ++q) {
      float sg2 = ((i >> (7-q)) & 1) ? -1.f : 1.f;
      s += sg2 * w3[q*256 + n];
    }
    Gm[idx] = f2bf(s);
  }
}

// ---------------------------------------------------------------------------
// enc_mfma: unchanged from R3 (validated) except launch_bounds (256,2).
// ---------------------------------------------------------------------------
__global__ __launch_bounds__(256, 2)
void enc_mfma(const float* __restrict__ state, const float* __restrict__ action,
              const unsigned short* __restrict__ w1p,
              const float* __restrict__ b1a, const float* __restrict__ b1b,
              const unsigned short* __restrict__ w2p,
              const float* __restrict__ b2a, const float* __restrict__ b2b,
              float* __restrict__ enc, int Bn) {
  __shared__ __align__(16) char Bx[2][16384];
  __shared__ __align__(16) float sb1[2][256];
  __shared__ float sb2[2][8];
  __shared__ __align__(16) float encw[4][2][32][8];
  int tid = threadIdx.x;
  int lane = tid & 63, w = tid >> 6, il = lane & 31, h5 = lane >> 5;
  int r0 = blockIdx.x * 64;

  sb1[0][tid] = b1a[tid];
  sb1[1][tid] = b1b[tid];
  if (tid < 8) { sb2[0][tid] = b2a[tid]; sb2[1][tid] = b2b[tid]; }

  {
    int m = tid >> 2, kq = tid & 3;
    const float4* st4 = (const float4*)state;
    const float4* ac4 = (const float4*)action;
    #pragma unroll
    for (int ks = 0; ks < 8; ++ks) {
      float4 v = (ks < 6) ? st4[(size_t)(r0+m)*24 + ks*4 + kq]
                          : ac4[(size_t)(r0+m)*8 + (ks-6)*4 + kq];
      unsigned short hx = f2bf(v.x), hy = f2bf(v.y), hz = f2bf(v.z), hw = f2bf(v.w);
      uint2 hh, ll;
      hh.x = (unsigned)hx | ((unsigned)hy << 16);
      hh.y = (unsigned)hz | ((unsigned)hw << 16);
      ll.x = (unsigned)f2bf(v.x - bf2f(hx)) | ((unsigned)f2bf(v.y - bf2f(hy)) << 16);
      ll.y = (unsigned)f2bf(v.z - bf2f(hz)) | ((unsigned)f2bf(v.w - bf2f(hw)) << 16);
      int off = ks*2048 + m*32 + kq*8;
      *(uint2*)(&Bx[0][off]) = hh;
      *(uint2*)(&Bx[1][off]) = ll;
    }
  }
  __syncthreads();

  for (int c = 0; c < 2; ++c) {
    accv_t A[2][2] = {{{},{}},{{},{}}};
    #pragma unroll
    for (int ks = 0; ks < 8; ++ks) {
      bfrag_t a0h, a0l, a1h, a1l;
      {
        size_t b0 = ((size_t)((c*2+0)*8 + ks)*2 + h5)*256;
        size_t b1 = ((size_t)((c*2+1)*8 + ks)*2 + h5)*256;
        int t0 = 2*w, t1 = 2*w+1;
        a0h = *(const bfrag_t*)(w1p + (b0 + t0*32 + il)*8);
        a0l = *(const bfrag_t*)(w1p + (b1 + t0*32 + il)*8);
        a1h = *(const bfrag_t*)(w1p + (b0 + t1*32 + il)*8);
        a1l = *(const bfrag_t*)(w1p + (b1 + t1*32 + il)*8);
      }
      bfrag_t b0h = *(const bfrag_t*)(&Bx[0][ks*2048 + il*32 + h5*16]);
      bfrag_t b0l = *(const bfrag_t*)(&Bx[1][ks*2048 + il*32 + h5*16]);
      bfrag_t b1h_ = *(const bfrag_t*)(&Bx[0][ks*2048 + (32+il)*32 + h5*16]);
      bfrag_t b1l_ = *(const bfrag_t*)(&Bx[1][ks*2048 + (32+il)*32 + h5*16]);
      A[0][0] = __builtin_amdgcn_mfma_f32_32x32x16_bf16(a0h, b0h, A[0][0], 0,0,0);
      A[0][0] = __builtin_amdgcn_mfma_f32_32x32x16_bf16(a0h, b0l, A[0][0], 0,0,0);
      A[0][0] = __builtin_amdgcn_mfma_f32_32x32x16_bf16(a0l, b0h, A[0][0], 0,0,0);
      A[0][1] = __builtin_amdgcn_mfma_f32_32x32x16_bf16(a0h, b1h_, A[0][1], 0,0,0);
      A[0][1] = __builtin_amdgcn_mfma_f32_32x32x16_bf16(a0h, b1l_, A[0][1], 0,0,0);
      A[0][1] = __builtin_amdgcn_mfma_f32_32x32x16_bf16(a0l, b1h_, A[0][1], 0,0,0);
      A[1][0] = __builtin_amdgcn_mfma_f32_32x32x16_bf16(a1h, b0h, A[1][0], 0,0,0);
      A[1][0] = __builtin_amdgcn_mfma_f32_32x32x16_bf16(a1h, b0l, A[1][0], 0,0,0);
      A[1][0] = __builtin_amdgcn_mfma_f32_32x32x16_bf16(a1l, b0h, A[1][0], 0,0,0);
      A[1][1] = __builtin_amdgcn_mfma_f32_32x32x16_bf16(a1h, b1h_, A[1][1], 0,0,0);
      A[1][1] = __builtin_amdgcn_mfma_f32_32x32x16_bf16(a1h, b1l_, A[1][1], 0,0,0);
      A[1][1] = __builtin_amdgcn_mfma_f32_32x32x16_bf16(a1l, b1h_, A[1][1], 0,0,0);
    }
    #pragma unroll
    for (int nt = 0; nt < 2; ++nt) {
      #pragma unroll
      for (int g = 0; g < 4; ++g) {
        float4 bb = *(const float4*)&sb1[c][(2*w+nt)*32 + 8*g + 4*h5];
        float bba[4] = {bb.x, bb.y, bb.z, bb.w};
        #pragma unroll
        for (int jj = 0; jj < 4; ++jj) {
          A[nt][0][4*g+jj] = fmaxf(A[nt][0][4*g+jj] + bba[jj], 0.f);
          A[nt][1][4*g+jj] = fmaxf(A[nt][1][4*g+jj] + bba[jj], 0.f);
        }
      }
    }
    accv_t Cm[2] = {{},{}};
    #pragma unroll
    for (int k2 = 0; k2 < 4; ++k2) {
      int k16 = 4*w + k2;
      bfrag_t g2h = *(const bfrag_t*)(w2p + ((size_t)((c*2+0)*16 + k16)*2 + h5)*256 + il*8);
      bfrag_t g2l = *(const bfrag_t*)(w2p + ((size_t)((c*2+1)*16 + k16)*2 + h5)*256 + il*8);
      #pragma unroll
      for (int mt = 0; mt < 2; ++mt) {
        unsigned ph[2][2], pl[2][2];
        #pragma unroll
        for (int gi = 0; gi < 2; ++gi) {
          int G = 2*k2 + gi, nt = G >> 2, g = G & 3;
          float f0 = A[nt][mt][4*g+0], f1 = A[nt][mt][4*g+1];
          float f2 = A[nt][mt][4*g+2], f3 = A[nt][mt][4*g+3];
          unsigned short h0 = f2bf(f0), h1 = f2bf(f1), h2 = f2bf(f2), h3 = f2bf(f3);
          ph[gi][0] = (unsigned)h0 | ((unsigned)h1 << 16);
          ph[gi][1] = (unsigned)h2 | ((unsigned)h3 << 16);
          pl[gi][0] = (unsigned)f2bf(f0 - bf2f(h0)) | ((unsigned)f2bf(f1 - bf2f(h1)) << 16);
          pl[gi][1] = (unsigned)f2bf(f2 - bf2f(h2)) | ((unsigned)f2bf(f3 - bf2f(h3)) << 16);
        }
        union { bfrag_t v; unsigned u[4]; } FH, FL;
        #pragma unroll
        for (int r = 0; r < 2; ++r) {
          unsigned own_h = h5 ? ph[1][r] : ph[0][r];
          unsigned alt_h = h5 ? ph[0][r] : ph[1][r];
          unsigned rec_h = __shfl_xor((int)alt_h, 32);
          FH.u[r]   = h5 ? rec_h : own_h;
          FH.u[2+r] = h5 ? own_h : rec_h;
          unsigned own_l = h5 ? pl[1][r] : pl[0][r];
          unsigned alt_l = h5 ? pl[0][r] : pl[1][r];
          unsigned rec_l = __shfl_xor((int)alt_l, 32);
          FL.u[r]   = h5 ? rec_l : own_l;
          FL.u[2+r] = h5 ? own_l : rec_l;
        }
        Cm[mt] = __builtin_amdgcn_mfma_f32_32x32x16_bf16(g2h, FH.v, Cm[mt], 0,0,0);
        Cm[mt] = __builtin_amdgcn_mfma_f32_32x32x16_bf16(g2h, FL.v, Cm[mt], 0,0,0);
        Cm[mt] = __builtin_amdgcn_mfma_f32_32x32x16_bf16(g2l, FH.v, Cm[mt], 0,0,0);
      }
    }
    *(float4*)&encw[w][0][il][4*h5] = make_float4(Cm[0][0], Cm[0][1], Cm[0][2], Cm[0][3]);
    *(float4*)&encw[w][1][il][4*h5] = make_float4(Cm[1][0], Cm[1][1], Cm[1][2], Cm[1][3]);
    __syncthreads();
    #pragma unroll
    for (int half = 0; half < 2; ++half) {
      int s = tid + half*256;
      int e = s & 7, mm = s >> 3;
      float v = sb2[c][e];
      #pragma unroll
      for (int ww = 0; ww < 4; ++ww) v += encw[ww][mm>>5][mm&31][e];
      enc[((size_t)c*Bn + r0 + mm)*8 + e] = v;
    }
    __syncthreads();
  }
}

// ---------------------------------------------------------------------------
// qgemm R4: 512 thr = 8 waves, grid 256 (c x 128 rowblocks), 16 subtiles of
// 32 rows. Wave w: stage1 N-tiles {w(re), 8+w(im)} from resident bf0/bf1;
// stage2 col-tile w with G streamed coalesced from global (frag-order Gm).
// LDS: APq 32KB = Alds(16K) | Plds(16K), reused as fp32 qtmp[32][256].
// ---------------------------------------------------------------------------
__global__ __launch_bounds__(512, 2)
void qgemm(const float* __restrict__ enc,
           const unsigned short* __restrict__ Bm, const unsigned short* __restrict__ Gm,
           const float* __restrict__ b3a, const float* __restrict__ w4a, const float* __restrict__ b4a,
           const float* __restrict__ b3b, const float* __restrict__ w4b, const float* __restrict__ b4b,
           float* __restrict__ out, int Bn) {
  __shared__ __align__(16) char APq[32768];
  char* Alds = APq;              // [g2*1024 + half*512 + m*16]
  char* Plds = APq + 16384;      // [ks*1024 + lane*16]
  float* qtmp = (float*)APq;     // [row*256 + n2]

  int tid = threadIdx.x;
  int lane = tid & 63;
  int w = tid >> 6;
  int il = lane & 31;
  int h5 = lane >> 5;

  int c = blockIdx.x >> 7;
  int rowblock = blockIdx.x & 127;
  int rowsPerBlock = Bn >> 7;        // 512
  int subtiles = rowsPerBlock >> 5;  // 16

  // ---- persistent W-frags: tile pair (w, 8+w), 128 VGPR ----
  bfrag_t bf0[16], bf1[16];
  {
    const unsigned short* base = Bm + ((size_t)(c*512 + 32*w + il)*256 + h5*8);
    #pragma unroll
    for (int ks = 0; ks < 16; ++ks) {
      bf0[ks] = *(const bfrag_t*)(base + ks*16);
      bf1[ks] = *(const bfrag_t*)(base + 256*256 + ks*16);
    }
  }
  int n2 = 32*w + il;
  const float* b3c = c ? b3b : b3a;
  const float* w4c = c ? w4b : w4a;
  const float* b4c = c ? b4b : b4a;
  float b3v = b3c[n2];
  float w4v = w4c[n2];
  float b4v = b4c[0];
  // coalesced G frag base for this wave's col-tile
  const unsigned short* Gbase = Gm + ((size_t)(c*8 + w)*16)*512 + lane*8;
  int pwbase = (n2>>4)*1024 + ((n2>>3)&1)*512 + (n2&7)*2;
  int rowAdd = 4*h5;

  for (int st = 0; st < subtiles; ++st) {
    int r0 = rowblock*rowsPerBlock + st*32;
    __syncthreads();                                   // (1) qtmp reads done
    // ---- build R tile (sincos inline) ----
    {
      int m = tid & 31, g2 = tid >> 5;                 // g2 in [0,16)
      const float* ep = enc + ((size_t)c*Bn + r0 + m)*8;
      float4 ea = *(const float4*)ep;
      float4 eb = *(const float4*)(ep + 4);
      float c0,s0,c1,s1,c2,s2,c3,s3,c4,s4,c5,s5,c6,s6,c7,s7;
      __sincosf(0.5f*ea.x, &s0, &c0);
      __sincosf(0.5f*ea.y, &s1, &c1);
      __sincosf(0.5f*ea.z, &s2, &c2);
      __sincosf(0.5f*ea.w, &s3, &c3);
      __sincosf(0.5f*eb.x, &s4, &c4);
      __sincosf(0.5f*eb.y, &s5, &c5);
      __sincosf(0.5f*eb.z, &s6, &c6);
      __sincosf(0.5f*eb.w, &s7, &c7);
      float v0 = (g2&8) ? s0 : c0;
      float v1 = (g2&4) ? s1 : c1;
      float v2 = (g2&2) ? s2 : c2;
      float v3 = (g2&1) ? s3 : c3;
      float top = v0*v1*v2*v3;
      float hA = top*c4, hB = top*s4;
      float p67[4];
      p67[0] = c6*c7; p67[1] = c6*s7; p67[2] = s6*c7; p67[3] = s6*s7;
      float low[8];
      #pragma unroll
      for (int j = 0; j < 8; ++j) low[j] = ((j&4) ? s5 : c5) * p67[j&3];
      union { bfrag_t v; unsigned u[4]; } pk;
      #pragma unroll
      for (int k = 0; k < 4; ++k) pk.u[k] = pack2(hA*low[2*k], hA*low[2*k+1]);
      *(bfrag_t*)(Alds + g2*1024 + m*16) = pk.v;
      #pragma unroll
      for (int k = 0; k < 4; ++k) pk.u[k] = pack2(hB*low[2*k], hB*low[2*k+1]);
      *(bfrag_t*)(Alds + g2*1024 + 512 + m*16) = pk.v;
    }
    __syncthreads();                                   // (2) A ready
    // ---- stage 1 (FULL unroll: bf indices must be constants) ----
    accv_t acc0 = {}, acc1 = {};
    #pragma unroll
    for (int ks = 0; ks < 16; ++ks) {
      bfrag_t af = *(const bfrag_t*)(Alds + ks*1024 + lane*16);
      acc0 = __builtin_amdgcn_mfma_f32_32x32x16_bf16(af, bf0[ks], acc0, 0, 0, 0);
      acc1 = __builtin_amdgcn_mfma_f32_32x32x16_bf16(af, bf1[ks], acc1, 0, 0, 0);
    }
    // ---- P = re^2+im^2 -> Plds (frag order) ----
    #pragma unroll
    for (int r = 0; r < 16; ++r) {
      float P = acc0[r]*acc0[r] + acc1[r]*acc1[r];
      int row = (r&3) + 8*(r>>2) + rowAdd;
      *(unsigned short*)(Plds + pwbase + row*16) = f2bf(P);
    }
    __syncthreads();                                   // (3) P ready
    // ---- stage 2: G streamed (no persistent arrays -> partial unroll safe) --
    accv_t acc2 = {};
    #pragma unroll 4
    for (int ks = 0; ks < 16; ++ks) {
      bfrag_t pf = *(const bfrag_t*)(Plds + ks*1024 + lane*16);
      bfrag_t gf = *(const bfrag_t*)(Gbase + ks*512);
      acc2 = __builtin_amdgcn_mfma_f32_32x32x16_bf16(pf, gf, acc2, 0, 0, 0);
    }
    float qp[16];
    #pragma unroll
    for (int r = 0; r < 16; ++r) qp[r] = fmaxf(acc2[r] + b3v, 0.f) * w4v;
    __syncthreads();                                   // (4) all P reads done
    #pragma unroll
    for (int r = 0; r < 16; ++r) {
      int row = (r&3) + 8*(r>>2) + rowAdd;
      qtmp[row*256 + n2] = qp[r];
    }
    __syncthreads();                                   // (5) qtmp ready
    // ---- reduce: thread t -> (row=t>>4, seg=t&15), sum 16 + 4-step shfl ----
    {
      int row = tid >> 4, seg = tid & 15;
      const float4* qp4 = (const float4*)(qtmp + row*256 + seg*16);
      float4 a0 = qp4[0], a1 = qp4[1], a2 = qp4[2], a3 = qp4[3];
      float s = (a0.x+a0.y+a0.z+a0.w) + (a1.x+a1.y+a1.z+a1.w)
              + (a2.x+a2.y+a2.z+a2.w) + (a3.x+a3.y+a3.z+a3.w);
      s += __shfl_xor(s, 1);
      s += __shfl_xor(s, 2);
      s += __shfl_xor(s, 4);
      s += __shfl_xor(s, 8);
      if (seg == 0) out[(size_t)c*Bn + r0 + row] = s + b4v;
    }
  }
}

extern "C" void kernel_launch(void* const* d_in, const int* in_sizes, int n_in,
                              void* d_out, int out_size, void* d_ws, size_t ws_size,
                              hipStream_t stream) {
  (void)n_in; (void)out_size; (void)ws_size;
  const float* state  = (const float*)d_in[0];
  const float* action = (const float*)d_in[1];
  const float* w1a=(const float*)d_in[2];  const float* b1a=(const float*)d_in[3];
  const float* w2a=(const float*)d_in[4];  const float* b2a=(const float*)d_in[5];
  const float* qrxa=(const float*)d_in[6]; const float* qrya=(const float*)d_in[7];
  const float* qrza=(const float*)d_in[8];
  const float* w3a=(const float*)d_in[9];  const float* b3a=(const float*)d_in[10];
  const float* w4a=(const float*)d_in[11]; const float* b4a=(const float*)d_in[12];
  const float* w1b=(const float*)d_in[13]; const float* b1b=(const float*)d_in[14];
  const float* w2b=(const float*)d_in[15]; const float* b2b=(const float*)d_in[16];
  const float* qrxb=(const float*)d_in[17];const float* qryb=(const float*)d_in[18];
  const float* qrzb=(const float*)d_in[19];
  const float* w3b=(const float*)d_in[20]; const float* b3b=(const float*)d_in[21];
  const float* w4b=(const float*)d_in[22]; const float* b4b=(const float*)d_in[23];

  int B = in_sizes[0] / 96;
  char* wsb = (char*)d_ws;
  unsigned short* Bmat = (unsigned short*)(wsb);                 // 524288 B
  unsigned short* Gmat = (unsigned short*)(wsb + 524288);        // 262144 B
  unsigned short* w1p  = (unsigned short*)(wsb + 786432);        // 262144 B
  unsigned short* w2p  = (unsigned short*)(wsb + 1048576);       // 65536 B
  float* enc           = (float*)(wsb + 1114112);                // 2*B*8*4 B

  prep_weights<<<712, 256, 0, stream>>>(qrxa,qrya,qrza,qrxb,qryb,qrzb,
                                        w1a,w1b,w2a,w2b,w3a,w3b,
                                        Bmat,Gmat,w1p,w2p);
  enc_mfma<<<B/64, 256, 0, stream>>>(state,action,w1p,b1a,b1b,w2p,b2a,b2b,enc,B);
  qgemm<<<256, 512, 0, stream>>>(enc, Bmat, Gmat, b3a, w4a, b4a, b3b, w4b, b4b,
                                 (float*)d_out, B);
}